// Round 3
// baseline (91.904 us; speedup 1.0000x reference)
//
#include <hip/hip_runtime.h>

#define DIM 16
#define NQ 4
#define NL 3
#define VQC_BATCH 524288
#define TPB 256
#define EPT 2              // elements per thread
#define EPB (TPB * EPT)    // 512 elements per block

// ---------------------------------------------------------------------------
// Build column `col` of the fixed 16x16 complex unitary U (3 layers of
// CNOT-ring + RY + RZ, batch-uniform weights). fp32 + native trig: weights
// are O(0.1), error ~1e-6 << 3.9e-3 tolerance.
// ---------------------------------------------------------------------------
__device__ __forceinline__ void build_U_column(const float* __restrict__ w,
                                               int col, float sr[DIM],
                                               float si[DIM]) {
#pragma unroll
  for (int k = 0; k < DIM; ++k) { sr[k] = (k == col) ? 1.f : 0.f; si[k] = 0.f; }
#pragma unroll
  for (int layer = 0; layer < NL; ++layer) {
    // CNOT ring: new[idx] = old[idx ^ (cbit(c) << (3-t))]
#pragma unroll
    for (int c = 0; c < NQ; ++c) {
      const int t = (c + 1) & 3;
      float tr[DIM], ti[DIM];
#pragma unroll
      for (int idx = 0; idx < DIM; ++idx) {
        const int cbit = (idx >> (3 - c)) & 1;
        const int src = idx ^ (cbit << (3 - t));
        tr[idx] = sr[src]; ti[idx] = si[src];
      }
#pragma unroll
      for (int idx = 0; idx < DIM; ++idx) { sr[idx] = tr[idx]; si[idx] = ti[idx]; }
    }
#pragma unroll
    for (int q = 0; q < NQ; ++q) {
      const int m = 8 >> q;
      {
        const float th = 0.5f * w[(layer * NQ + q) * 2 + 0];
        const float s = __sinf(th), c = __cosf(th);
#pragma unroll
        for (int idx = 0; idx < DIM; ++idx) {
          if ((idx & m) == 0) {
            const int i1 = idx | m;
            const float a0r = sr[idx], a0i = si[idx];
            const float a1r = sr[i1], a1i = si[i1];
            sr[idx] = c * a0r - s * a1r;  si[idx] = c * a0i - s * a1i;
            sr[i1]  = s * a0r + c * a1r;  si[i1]  = s * a0i + c * a1i;
          }
        }
      }
      {
        const float ph = 0.5f * w[(layer * NQ + q) * 2 + 1];
        const float sh = __sinf(ph), ch = __cosf(ph);
#pragma unroll
        for (int idx = 0; idx < DIM; ++idx) {
          const float ar = sr[idx], ai = si[idx];
          if (idx & m) { sr[idx] = ch * ar - sh * ai; si[idx] = ch * ai + sh * ar; }
          else         { sr[idx] = ch * ar + sh * ai; si[idx] = ch * ai - sh * ar; }
        }
      }
    }
  }
}

// product state from RY(x)|0>: idx bit3 = wire0 ... bit0 = wire3
__device__ __forceinline__ void state_from_x(const float4 xv, float sv[DIM]) {
  const float s0 = __sinf(0.5f * xv.x), c0 = __cosf(0.5f * xv.x);
  const float s1 = __sinf(0.5f * xv.y), c1 = __cosf(0.5f * xv.y);
  const float s2 = __sinf(0.5f * xv.z), c2 = __cosf(0.5f * xv.z);
  const float s3 = __sinf(0.5f * xv.w), c3 = __cosf(0.5f * xv.w);
  float ab[4], cd[4];
  ab[0] = c0 * c1; ab[1] = c0 * s1; ab[2] = s0 * c1; ab[3] = s0 * s1;
  cd[0] = c2 * c3; cd[1] = c2 * s3; cd[2] = s2 * c3; cd[3] = s2 * s3;
#pragma unroll
  for (int hi = 0; hi < 4; ++hi)
#pragma unroll
    for (int lo = 0; lo < 4; ++lo)
      sv[hi * 4 + lo] = ab[hi] * cd[lo];
}

// z_w = sum_j (1-2*bit_{3-w}(j)) * p_j  (sign butterfly)
__device__ __forceinline__ float4 z_from_p(const float p[DIM]) {
  float a[8], z3 = 0.f;
#pragma unroll
  for (int t = 0; t < 8; ++t) { a[t] = p[2 * t] + p[2 * t + 1]; z3 += p[2 * t] - p[2 * t + 1]; }
  float b2[4], z2 = 0.f;
#pragma unroll
  for (int t = 0; t < 4; ++t) { b2[t] = a[2 * t] + a[2 * t + 1]; z2 += a[2 * t] - a[2 * t + 1]; }
  const float e0 = b2[0] + b2[1], e1 = b2[2] + b2[3];
  const float z1 = (b2[0] - b2[1]) + (b2[2] - b2[3]);
  const float z0 = e0 - e1;
  return make_float4(z0, z1, z2, z3);
}

// ---------------------------------------------------------------------------
// Fused kernel: lanes 0-15 rebuild U into LDS (once per block, ~amortized
// over 512 elements), then each thread computes 2 batch elements, sharing
// each broadcast U-row read across both.
// ---------------------------------------------------------------------------
__global__ __launch_bounds__(TPB) void vqc_fused(const float4* __restrict__ x4,
                                                 const float* __restrict__ w,
                                                 float4* __restrict__ out4) {
  __shared__ float Uld[DIM * DIM * 2];  // row-major, re/im interleaved

  const int tid = threadIdx.x;
  if (tid < DIM) {
    float sr[DIM], si[DIM];
    build_U_column(w, tid, sr, si);
#pragma unroll
    for (int j = 0; j < DIM; ++j) {
      Uld[(j * DIM + tid) * 2 + 0] = sr[j];
      Uld[(j * DIM + tid) * 2 + 1] = si[j];
    }
  }
  __syncthreads();
  const float4* U4 = (const float4*)Uld;

  const int e0 = blockIdx.x * EPB + tid;
  const int e1 = e0 + TPB;

  float sv0[DIM], sv1[DIM];
  state_from_x(x4[e0], sv0);
  state_from_x(x4[e1], sv1);

  float p0[DIM], p1[DIM];
#pragma unroll
  for (int j = 0; j < DIM; ++j) {
    float vr0 = 0.f, vi0 = 0.f, vr1 = 0.f, vi1 = 0.f;
#pragma unroll
    for (int iv = 0; iv < 8; ++iv) {
      const float4 u = U4[j * 8 + iv];  // broadcast ds_read_b128
      const float a0 = sv0[2 * iv], b0 = sv0[2 * iv + 1];
      const float a1 = sv1[2 * iv], b1 = sv1[2 * iv + 1];
      vr0 = __builtin_fmaf(u.x, a0, vr0); vi0 = __builtin_fmaf(u.y, a0, vi0);
      vr0 = __builtin_fmaf(u.z, b0, vr0); vi0 = __builtin_fmaf(u.w, b0, vi0);
      vr1 = __builtin_fmaf(u.x, a1, vr1); vi1 = __builtin_fmaf(u.y, a1, vi1);
      vr1 = __builtin_fmaf(u.z, b1, vr1); vi1 = __builtin_fmaf(u.w, b1, vi1);
    }
    p0[j] = vr0 * vr0 + vi0 * vi0;
    p1[j] = vr1 * vr1 + vi1 * vi1;
  }

  out4[e0] = z_from_p(p0);
  out4[e1] = z_from_p(p1);
}

extern "C" void kernel_launch(void* const* d_in, const int* in_sizes, int n_in,
                              void* d_out, int out_size, void* d_ws, size_t ws_size,
                              hipStream_t stream) {
  const float* x = (const float*)d_in[0];
  const float* w = (const float*)d_in[1];
  vqc_fused<<<VQC_BATCH / EPB, TPB, 0, stream>>>((const float4*)x, w,
                                                 (float4*)d_out);
}

// Round 5
// 72.512 us; speedup vs baseline: 1.2674x; 1.2674x over previous
//
#include <hip/hip_runtime.h>

#define DIM 16
#define NQ 4
#define NL 3
#define VQC_BATCH 524288

// Constant-address-space pointer to a PRIMITIVE type (float4 is a class and
// can't bind AS4 references; float can). Uniform constant-AS loads select the
// SMEM path -> s_load_dwordx4/x8 -> U lives in SGPRs, scalar pipe, not 128
// VMEM instructions per wave.
typedef const __attribute__((address_space(4))) float* cas_float_p;

// ---------------------------------------------------------------------------
// Prep kernel: build the fixed 16x16 complex unitary U for the 3 weight
// layers (CNOT ring + RY + RZ). One thread per column, fp32 + native trig
// (weights O(0.1): error ~1e-6 << 3.9e-3 tolerance).
// Layout (row-major, re/im interleaved): U[(j*16+i)*2 + {0,1}] = U_{j,i}
// ---------------------------------------------------------------------------
__global__ __launch_bounds__(64) void vqc_prep(const float* __restrict__ w,
                                               float* __restrict__ U) {
  const int col = threadIdx.x;
  if (col >= DIM) return;
  float sr[DIM], si[DIM];
#pragma unroll
  for (int k = 0; k < DIM; ++k) { sr[k] = (k == col) ? 1.f : 0.f; si[k] = 0.f; }

#pragma unroll
  for (int layer = 0; layer < NL; ++layer) {
#pragma unroll
    for (int c = 0; c < NQ; ++c) {  // CNOT ring
      const int t = (c + 1) & 3;
      float tr[DIM], ti[DIM];
#pragma unroll
      for (int idx = 0; idx < DIM; ++idx) {
        const int cbit = (idx >> (3 - c)) & 1;
        const int src = idx ^ (cbit << (3 - t));
        tr[idx] = sr[src]; ti[idx] = si[src];
      }
#pragma unroll
      for (int idx = 0; idx < DIM; ++idx) { sr[idx] = tr[idx]; si[idx] = ti[idx]; }
    }
#pragma unroll
    for (int q = 0; q < NQ; ++q) {  // RY then RZ on qubit q
      const int m = 8 >> q;
      {
        const float th = 0.5f * w[(layer * NQ + q) * 2 + 0];
        const float s = __sinf(th), c = __cosf(th);
#pragma unroll
        for (int idx = 0; idx < DIM; ++idx) {
          if ((idx & m) == 0) {
            const int i1 = idx | m;
            const float a0r = sr[idx], a0i = si[idx];
            const float a1r = sr[i1], a1i = si[i1];
            sr[idx] = c * a0r - s * a1r;  si[idx] = c * a0i - s * a1i;
            sr[i1]  = s * a0r + c * a1r;  si[i1]  = s * a0i + c * a1i;
          }
        }
      }
      {
        const float ph = 0.5f * w[(layer * NQ + q) * 2 + 1];
        const float sh = __sinf(ph), ch = __cosf(ph);
#pragma unroll
        for (int idx = 0; idx < DIM; ++idx) {
          const float ar = sr[idx], ai = si[idx];
          if (idx & m) { sr[idx] = ch * ar - sh * ai; si[idx] = ch * ai + sh * ar; }
          else         { sr[idx] = ch * ar + sh * ai; si[idx] = ch * ai - sh * ar; }
        }
      }
    }
  }
#pragma unroll
  for (int j = 0; j < DIM; ++j) {
    U[(j * DIM + col) * 2 + 0] = sr[j];
    U[(j * DIM + col) * 2 + 1] = si[j];
  }
}

// ---------------------------------------------------------------------------
// Main kernel: one thread per batch element.
//   s = product state from RY(x)|0>  (real, rank-1)         ~45 VALU
//   v = U s  (complex matvec; U via s_load -> SGPR operand)  512 v_fmac
//   p = |v|^2, sign-butterfly -> 4 Z-expectations            ~70 VALU
// ---------------------------------------------------------------------------
__global__ __launch_bounds__(256) void vqc_main(const float4* __restrict__ x4,
                                                const float* __restrict__ U,
                                                float4* __restrict__ out4) {
  const int b = blockIdx.x * 256 + threadIdx.x;
  const float4 xv = x4[b];

  const float s0 = __sinf(0.5f * xv.x), c0 = __cosf(0.5f * xv.x);
  const float s1 = __sinf(0.5f * xv.y), c1 = __cosf(0.5f * xv.y);
  const float s2 = __sinf(0.5f * xv.z), c2 = __cosf(0.5f * xv.z);
  const float s3 = __sinf(0.5f * xv.w), c3 = __cosf(0.5f * xv.w);

  // product state: idx bit3 = wire0 ... bit0 = wire3; bit=0 -> cos, 1 -> sin
  float ab[4], cd[4];
  ab[0] = c0 * c1; ab[1] = c0 * s1; ab[2] = s0 * c1; ab[3] = s0 * s1;
  cd[0] = c2 * c3; cd[1] = c2 * s3; cd[2] = s2 * c3; cd[3] = s2 * s3;
  float sv[DIM];
#pragma unroll
  for (int hi = 0; hi < 4; ++hi)
#pragma unroll
    for (int lo = 0; lo < 4; ++lo)
      sv[hi * 4 + lo] = ab[hi] * cd[lo];

  // v = U s ; p = |v|^2. U through constant-AS scalar loads (SGPRs).
  cas_float_p Uc = (cas_float_p)(unsigned long long)U;
  float p[DIM];
#pragma unroll
  for (int j = 0; j < DIM; ++j) {
    float vr = 0.f, vi = 0.f;
#pragma unroll
    for (int i = 0; i < DIM; ++i) {
      const float ur = Uc[(j * DIM + i) * 2 + 0];
      const float ui = Uc[(j * DIM + i) * 2 + 1];
      vr = __builtin_fmaf(ur, sv[i], vr);
      vi = __builtin_fmaf(ui, sv[i], vi);
    }
    p[j] = vr * vr + vi * vi;
  }

  // sign butterfly: z_w = sum_j (1-2*bit_{3-w}(j)) * p_j
  float a[8], z3 = 0.f;
#pragma unroll
  for (int t = 0; t < 8; ++t) { a[t] = p[2 * t] + p[2 * t + 1]; z3 += p[2 * t] - p[2 * t + 1]; }
  float b2[4], z2 = 0.f;
#pragma unroll
  for (int t = 0; t < 4; ++t) { b2[t] = a[2 * t] + a[2 * t + 1]; z2 += a[2 * t] - a[2 * t + 1]; }
  const float e0 = b2[0] + b2[1], e1 = b2[2] + b2[3];
  const float z1 = (b2[0] - b2[1]) + (b2[2] - b2[3]);
  const float z0 = e0 - e1;

  out4[b] = make_float4(z0, z1, z2, z3);
}

extern "C" void kernel_launch(void* const* d_in, const int* in_sizes, int n_in,
                              void* d_out, int out_size, void* d_ws, size_t ws_size,
                              hipStream_t stream) {
  const float* x = (const float*)d_in[0];
  const float* w = (const float*)d_in[1];
  float* U = (float*)d_ws;  // 512 floats = 2 KB scratch

  vqc_prep<<<1, 64, 0, stream>>>(w, U);
  vqc_main<<<VQC_BATCH / 256, 256, 0, stream>>>((const float4*)x, U,
                                                (float4*)d_out);
}

// Round 6
// 71.126 us; speedup vs baseline: 1.2921x; 1.0195x over previous
//
#include <hip/hip_runtime.h>

#define DIM 16
#define NQ 4
#define NL 3
#define VQC_BATCH 524288

// clang ext-vector float2: a primitive vector type (unlike HIP's float4
// class), so it can live behind an address_space(4) pointer, and arithmetic
// on it legalizes to v_pk_*_f32 packed-fp32 instructions on gfx950.
typedef float v2f __attribute__((ext_vector_type(2)));
typedef const __attribute__((address_space(4))) v2f* cas_v2_p;

// ---------------------------------------------------------------------------
// Prep kernel: build the fixed 16x16 complex unitary U for the 3 weight
// layers (CNOT ring + RY + RZ). One thread per column, fp32 + native trig
// (weights O(0.1): error ~1e-6 << 3.9e-3 tolerance).
// Layout (row-major, re/im interleaved): U[(j*16+i)*2 + {0,1}] = U_{j,i}
// ---------------------------------------------------------------------------
__global__ __launch_bounds__(64) void vqc_prep(const float* __restrict__ w,
                                               float* __restrict__ U) {
  const int col = threadIdx.x;
  if (col >= DIM) return;
  float sr[DIM], si[DIM];
#pragma unroll
  for (int k = 0; k < DIM; ++k) { sr[k] = (k == col) ? 1.f : 0.f; si[k] = 0.f; }

#pragma unroll
  for (int layer = 0; layer < NL; ++layer) {
#pragma unroll
    for (int c = 0; c < NQ; ++c) {  // CNOT ring
      const int t = (c + 1) & 3;
      float tr[DIM], ti[DIM];
#pragma unroll
      for (int idx = 0; idx < DIM; ++idx) {
        const int cbit = (idx >> (3 - c)) & 1;
        const int src = idx ^ (cbit << (3 - t));
        tr[idx] = sr[src]; ti[idx] = si[src];
      }
#pragma unroll
      for (int idx = 0; idx < DIM; ++idx) { sr[idx] = tr[idx]; si[idx] = ti[idx]; }
    }
#pragma unroll
    for (int q = 0; q < NQ; ++q) {  // RY then RZ on qubit q
      const int m = 8 >> q;
      {
        const float th = 0.5f * w[(layer * NQ + q) * 2 + 0];
        const float s = __sinf(th), c = __cosf(th);
#pragma unroll
        for (int idx = 0; idx < DIM; ++idx) {
          if ((idx & m) == 0) {
            const int i1 = idx | m;
            const float a0r = sr[idx], a0i = si[idx];
            const float a1r = sr[i1], a1i = si[i1];
            sr[idx] = c * a0r - s * a1r;  si[idx] = c * a0i - s * a1i;
            sr[i1]  = s * a0r + c * a1r;  si[i1]  = s * a0i + c * a1i;
          }
        }
      }
      {
        const float ph = 0.5f * w[(layer * NQ + q) * 2 + 1];
        const float sh = __sinf(ph), ch = __cosf(ph);
#pragma unroll
        for (int idx = 0; idx < DIM; ++idx) {
          const float ar = sr[idx], ai = si[idx];
          if (idx & m) { sr[idx] = ch * ar - sh * ai; si[idx] = ch * ai + sh * ar; }
          else         { sr[idx] = ch * ar + sh * ai; si[idx] = ch * ai - sh * ar; }
        }
      }
    }
  }
#pragma unroll
  for (int j = 0; j < DIM; ++j) {
    U[(j * DIM + col) * 2 + 0] = sr[j];
    U[(j * DIM + col) * 2 + 1] = si[j];
  }
}

// ---------------------------------------------------------------------------
// Main kernel: one thread per batch element.
//   s = product state from RY(x)|0>  (real, rank-1)            ~55 VALU
//   v = U s  complex matvec as 256 v_pk_fma_f32 (re,im packed,
//       U rows via scalar s_load -> SGPR-pair operand)          256 VALU
//   p = |v|^2 (pk_mul + add), sign-butterfly -> 4 Z-exps        ~76 VALU
// ---------------------------------------------------------------------------
__global__ __launch_bounds__(256) void vqc_main(const float4* __restrict__ x4,
                                                const float* __restrict__ U,
                                                float4* __restrict__ out4) {
  const int b = blockIdx.x * 256 + threadIdx.x;
  const float4 xv = x4[b];

  const float s0 = __sinf(0.5f * xv.x), c0 = __cosf(0.5f * xv.x);
  const float s1 = __sinf(0.5f * xv.y), c1 = __cosf(0.5f * xv.y);
  const float s2 = __sinf(0.5f * xv.z), c2 = __cosf(0.5f * xv.z);
  const float s3 = __sinf(0.5f * xv.w), c3 = __cosf(0.5f * xv.w);

  // product state: idx bit3 = wire0 ... bit0 = wire3; bit=0 -> cos, 1 -> sin
  float ab[4], cd[4];
  ab[0] = c0 * c1; ab[1] = c0 * s1; ab[2] = s0 * c1; ab[3] = s0 * s1;
  cd[0] = c2 * c3; cd[1] = c2 * s3; cd[2] = s2 * c3; cd[3] = s2 * s3;
  float sv[DIM];
#pragma unroll
  for (int hi = 0; hi < 4; ++hi)
#pragma unroll
    for (int lo = 0; lo < 4; ++lo)
      sv[hi * 4 + lo] = ab[hi] * cd[lo];

  // v = U s as packed (re,im) accumulation: acc = fma(u2, {s_i,s_i}, acc)
  // -> v_pk_fma_f32 with the (ur,ui) SGPR pair from scalar U loads.
  cas_v2_p Uc = (cas_v2_p)(unsigned long long)U;
  float p[DIM];
#pragma unroll
  for (int j = 0; j < DIM; ++j) {
    v2f acc = {0.f, 0.f};
#pragma unroll
    for (int i = 0; i < DIM; ++i) {
      const v2f u = Uc[j * DIM + i];
      const v2f sb = {sv[i], sv[i]};
      acc = __builtin_elementwise_fma(u, sb, acc);
    }
    const v2f sq = acc * acc;      // v_pk_mul_f32
    p[j] = sq.x + sq.y;
  }

  // sign butterfly: z_w = sum_j (1-2*bit_{3-w}(j)) * p_j
  float a[8], z3 = 0.f;
#pragma unroll
  for (int t = 0; t < 8; ++t) { a[t] = p[2 * t] + p[2 * t + 1]; z3 += p[2 * t] - p[2 * t + 1]; }
  float b2[4], z2 = 0.f;
#pragma unroll
  for (int t = 0; t < 4; ++t) { b2[t] = a[2 * t] + a[2 * t + 1]; z2 += a[2 * t] - a[2 * t + 1]; }
  const float e0 = b2[0] + b2[1], e1 = b2[2] + b2[3];
  const float z1 = (b2[0] - b2[1]) + (b2[2] - b2[3]);
  const float z0 = e0 - e1;

  out4[b] = make_float4(z0, z1, z2, z3);
}

extern "C" void kernel_launch(void* const* d_in, const int* in_sizes, int n_in,
                              void* d_out, int out_size, void* d_ws, size_t ws_size,
                              hipStream_t stream) {
  const float* x = (const float*)d_in[0];
  const float* w = (const float*)d_in[1];
  float* U = (float*)d_ws;  // 512 floats = 2 KB scratch

  vqc_prep<<<1, 64, 0, stream>>>(w, U);
  vqc_main<<<VQC_BATCH / 256, 256, 0, stream>>>((const float4*)x, U,
                                                (float4*)d_out);
}

// Round 7
// 71.056 us; speedup vs baseline: 1.2934x; 1.0010x over previous
//
#include <hip/hip_runtime.h>

#define DIM 16
#define NQ 4
#define NL 3
#define VQC_BATCH 524288

// clang ext-vector float2: primitive vector type -> binds address_space(4)
// pointers and legalizes arithmetic to v_pk_*_f32 packed-fp32 on gfx950.
typedef float v2f __attribute__((ext_vector_type(2)));
typedef const __attribute__((address_space(4))) v2f* cas_v2_p;

// ---------------------------------------------------------------------------
// Prep kernel: build the fixed 16x16 complex unitary U (3 layers of CNOT
// ring + RY + RZ, batch-uniform weights). One thread per column, fp32 +
// native trig (weights O(0.1): trig error ~1e-6 << tolerance).
// All 24 sincos hoisted out of the 24-gate dependent chain.
// Layout (row-major, re/im interleaved): U[(j*16+i)*2 + {0,1}] = U_{j,i}
// ---------------------------------------------------------------------------
__global__ __launch_bounds__(64) void vqc_prep(const float* __restrict__ w,
                                               float* __restrict__ U) {
  const int col = threadIdx.x;
  if (col >= DIM) return;

  // hoisted trig: independent of the state chain -> pipelined up front
  float cy[NL * NQ], sy[NL * NQ], cz[NL * NQ], sz[NL * NQ];
#pragma unroll
  for (int k = 0; k < NL * NQ; ++k) {
    const float ty = 0.5f * w[k * 2 + 0];
    const float tz = 0.5f * w[k * 2 + 1];
    cy[k] = __cosf(ty); sy[k] = __sinf(ty);
    cz[k] = __cosf(tz); sz[k] = __sinf(tz);
  }

  float sr[DIM], si[DIM];
#pragma unroll
  for (int k = 0; k < DIM; ++k) { sr[k] = (k == col) ? 1.f : 0.f; si[k] = 0.f; }

#pragma unroll
  for (int layer = 0; layer < NL; ++layer) {
#pragma unroll
    for (int c = 0; c < NQ; ++c) {  // CNOT ring (register rename only)
      const int t = (c + 1) & 3;
      float tr[DIM], ti[DIM];
#pragma unroll
      for (int idx = 0; idx < DIM; ++idx) {
        const int cbit = (idx >> (3 - c)) & 1;
        const int src = idx ^ (cbit << (3 - t));
        tr[idx] = sr[src]; ti[idx] = si[src];
      }
#pragma unroll
      for (int idx = 0; idx < DIM; ++idx) { sr[idx] = tr[idx]; si[idx] = ti[idx]; }
    }
#pragma unroll
    for (int q = 0; q < NQ; ++q) {  // RY then RZ on qubit q
      const int m = 8 >> q;
      const int k = layer * NQ + q;
      const float c = cy[k], s = sy[k];
#pragma unroll
      for (int idx = 0; idx < DIM; ++idx) {
        if ((idx & m) == 0) {
          const int i1 = idx | m;
          const float a0r = sr[idx], a0i = si[idx];
          const float a1r = sr[i1], a1i = si[i1];
          sr[idx] = c * a0r - s * a1r;  si[idx] = c * a0i - s * a1i;
          sr[i1]  = s * a0r + c * a1r;  si[i1]  = s * a0i + c * a1i;
        }
      }
      const float ch = cz[k], sh = sz[k];
#pragma unroll
      for (int idx = 0; idx < DIM; ++idx) {
        const float ar = sr[idx], ai = si[idx];
        if (idx & m) { sr[idx] = ch * ar - sh * ai; si[idx] = ch * ai + sh * ar; }
        else         { sr[idx] = ch * ar + sh * ai; si[idx] = ch * ai - sh * ar; }
      }
    }
  }
  v2f* U2 = (v2f*)U;
#pragma unroll
  for (int j = 0; j < DIM; ++j) {
    v2f e; e.x = sr[j]; e.y = si[j];
    U2[j * DIM + col] = e;
  }
}

// ---------------------------------------------------------------------------
// Main kernel: one thread per batch element.
//   s = product state from RY(x)|0>  (real, rank-1)          ~55 VALU
//   v = U s: 256 v_pk_fma_f32 (U via scalar s_load -> SGPRs) 256 VALU
//   p = |v|^2 + packed sign-butterfly -> 4 Z-expectations     ~55 VALU
// ---------------------------------------------------------------------------
__global__ __launch_bounds__(256) void vqc_main(const float4* __restrict__ x4,
                                                const float* __restrict__ U,
                                                float4* __restrict__ out4) {
  const int b = blockIdx.x * 256 + threadIdx.x;
  const float4 xv = x4[b];

  const float s0 = __sinf(0.5f * xv.x), c0 = __cosf(0.5f * xv.x);
  const float s1 = __sinf(0.5f * xv.y), c1 = __cosf(0.5f * xv.y);
  const float s2 = __sinf(0.5f * xv.z), c2 = __cosf(0.5f * xv.z);
  const float s3 = __sinf(0.5f * xv.w), c3 = __cosf(0.5f * xv.w);

  // product state: idx bit3 = wire0 ... bit0 = wire3; bit=0 -> cos, 1 -> sin
  float ab[4], cd[4];
  ab[0] = c0 * c1; ab[1] = c0 * s1; ab[2] = s0 * c1; ab[3] = s0 * s1;
  cd[0] = c2 * c3; cd[1] = c2 * s3; cd[2] = s2 * c3; cd[3] = s2 * s3;
  float sv[DIM];
#pragma unroll
  for (int hi = 0; hi < 4; ++hi)
#pragma unroll
    for (int lo = 0; lo < 4; ++lo)
      sv[hi * 4 + lo] = ab[hi] * cd[lo];

  // v = U s packed (re,im); |v|^2 per j-pair packed into P[t] = {p2t, p2t+1}
  cas_v2_p Uc = (cas_v2_p)(unsigned long long)U;
  v2f P[8];
#pragma unroll
  for (int t = 0; t < 8; ++t) {
    v2f acc0 = {0.f, 0.f}, acc1 = {0.f, 0.f};
#pragma unroll
    for (int i = 0; i < DIM; ++i) {
      const v2f sb = {sv[i], sv[i]};
      acc0 = __builtin_elementwise_fma(Uc[(2 * t) * DIM + i], sb, acc0);
      acc1 = __builtin_elementwise_fma(Uc[(2 * t + 1) * DIM + i], sb, acc1);
    }
    const v2f q0 = acc0 * acc0, q1 = acc1 * acc1;  // v_pk_mul_f32
    P[t].x = q0.x + q0.y;
    P[t].y = q1.x + q1.y;
  }

  // packed sign butterfly. j bits: bit3->z0, bit2->z1, bit1->z2, bit0->z3.
  const v2f C0 = P[0] + P[1], C1 = P[2] + P[3];
  const v2f C2 = P[4] + P[5], C3 = P[6] + P[7];
  const v2f C01 = C0 + C1, C23 = C2 + C3;
  const v2f S  = C01 + C23;                      // {sum even j, sum odd j}
  const v2f D0 = C01 - C23;                      // z0 = D0.x + D0.y
  const v2f D1 = (C0 + C2) - (C1 + C3);          // z1 = D1.x + D1.y
  const v2f Ea = P[0] + P[2], Eb = P[4] + P[6];
  const v2f Oa = P[1] + P[3], Ob = P[5] + P[7];
  const v2f D2 = (Ea + Eb) - (Oa + Ob);          // z2 = D2.x + D2.y
  const float z0 = D0.x + D0.y;
  const float z1 = D1.x + D1.y;
  const float z2 = D2.x + D2.y;
  const float z3 = S.x - S.y;                    // even - odd (bit0)

  out4[b] = make_float4(z0, z1, z2, z3);
}

extern "C" void kernel_launch(void* const* d_in, const int* in_sizes, int n_in,
                              void* d_out, int out_size, void* d_ws, size_t ws_size,
                              hipStream_t stream) {
  const float* x = (const float*)d_in[0];
  const float* w = (const float*)d_in[1];
  float* U = (float*)d_ws;  // 512 floats = 2 KB scratch

  vqc_prep<<<1, 64, 0, stream>>>(w, U);
  vqc_main<<<VQC_BATCH / 256, 256, 0, stream>>>((const float4*)x, U,
                                                (float4*)d_out);
}